// Round 1
// baseline (15451.270 us; speedup 1.0000x reference)
//
#include <hip/hip_runtime.h>

#define BB   64
#define TT   512
#define KIN  256
#define HH   1024
#define NOUT 10

// x[b][t][k] (f32) -> xT[t][k][b] so scan-time loads coalesce over lane=b.
__global__ void k_transpose_x(const float* __restrict__ x, float* __restrict__ xT) {
    __shared__ float tile[64][65];
    const int blk  = blockIdx.x;       // t*4 + ktile
    const int t    = blk >> 2;
    const int k0   = (blk & 3) << 6;
    const int lane = threadIdx.x & 63;
    const int row0 = threadIdx.x >> 6; // 0..3
#pragma unroll
    for (int i = 0; i < 16; ++i) {
        int b = row0 + (i << 2);
        tile[b][lane] = x[((size_t)b * TT + t) * KIN + k0 + lane];
    }
    __syncthreads();
#pragma unroll
    for (int i = 0; i < 16; ++i) {
        int k = row0 + (i << 2);
        xT[((size_t)t * KIN + k0 + k) * BB + lane] = tile[lane][k];
    }
}

// One GRU timestep. Grid = 256 blocks; block owns 4 hidden columns j0..j0+3
// (12 weight rows across r/i/n gates). 256 threads = 64 batch lanes x 4 waves.
// Waves split the K dimension (h read exactly once per block); partial sums
// reduced through LDS; finish phase maps wave -> jj.
// h layout: [H][B] f32. Read hsrc, write hdst (ping-pong, no intra-step race).
__global__ __launch_bounds__(256) void k_gru_step(
    const float* __restrict__ xT, const float* __restrict__ Wx,
    const float* __restrict__ bx, const float* __restrict__ Wh,
    const float* __restrict__ bh, const float* __restrict__ hsrc,
    float* __restrict__ hdst, int t)
{
    __shared__ float wx_s[12][KIN];       // 12 KB
    __shared__ float wh_s[12][HH];        // 48 KB
    __shared__ float red[4][4][4][64];    // [jj][comp][wave][b] 16 KB

    const int tid = threadIdx.x;
    const int b   = tid & 63;
    const int w   = tid >> 6;
    const int j0  = blockIdx.x << 2;

    // Stage Wx rows (g*4+jj) -> 768 float4
#pragma unroll
    for (int i = 0; i < 3; ++i) {
        int f = tid + (i << 8);
        int r = f >> 6;
        int c = (f & 63) << 2;
        int g = r >> 2, jj = r & 3;
        *(float4*)&wx_s[r][c] =
            *(const float4*)&Wx[(size_t)(j0 + jj + (g << 10)) * KIN + c];
    }
    // Stage Wh rows -> 3072 float4
#pragma unroll
    for (int i = 0; i < 12; ++i) {
        int f = tid + (i << 8);
        int r = f >> 8;
        int c = (f & 255) << 2;
        int g = r >> 2, jj = r & 3;
        *(float4*)&wh_s[r][c] =
            *(const float4*)&Wh[(size_t)(j0 + jj + (g << 10)) * HH + c];
    }
    __syncthreads();

    float a_r[4]  = {0.f, 0.f, 0.f, 0.f};
    float a_i[4]  = {0.f, 0.f, 0.f, 0.f};
    float a_in[4] = {0.f, 0.f, 0.f, 0.f};
    float a_hn[4] = {0.f, 0.f, 0.f, 0.f};

    // x-dot: K=256 split 4 ways (64 per wave)
    const float* xrow = xT + (size_t)t * KIN * BB;
    for (int k = w << 6; k < (w << 6) + 64; k += 4) {
        float xv0 = xrow[(k + 0) * BB + b];
        float xv1 = xrow[(k + 1) * BB + b];
        float xv2 = xrow[(k + 2) * BB + b];
        float xv3 = xrow[(k + 3) * BB + b];
#pragma unroll
        for (int jj = 0; jj < 4; ++jj) {
            float4 vr = *(const float4*)&wx_s[jj][k];
            float4 vi = *(const float4*)&wx_s[4 + jj][k];
            float4 vn = *(const float4*)&wx_s[8 + jj][k];
            a_r[jj]  += vr.x * xv0 + vr.y * xv1 + vr.z * xv2 + vr.w * xv3;
            a_i[jj]  += vi.x * xv0 + vi.y * xv1 + vi.z * xv2 + vi.w * xv3;
            a_in[jj] += vn.x * xv0 + vn.y * xv1 + vn.z * xv2 + vn.w * xv3;
        }
    }
    // h-dot: K=1024 split 4 ways (256 per wave)
    for (int k = w << 8; k < (w << 8) + 256; k += 4) {
        float hv0 = hsrc[(k + 0) * BB + b];
        float hv1 = hsrc[(k + 1) * BB + b];
        float hv2 = hsrc[(k + 2) * BB + b];
        float hv3 = hsrc[(k + 3) * BB + b];
#pragma unroll
        for (int jj = 0; jj < 4; ++jj) {
            float4 vr = *(const float4*)&wh_s[jj][k];
            float4 vi = *(const float4*)&wh_s[4 + jj][k];
            float4 vn = *(const float4*)&wh_s[8 + jj][k];
            a_r[jj]  += vr.x * hv0 + vr.y * hv1 + vr.z * hv2 + vr.w * hv3;
            a_i[jj]  += vi.x * hv0 + vi.y * hv1 + vi.z * hv2 + vi.w * hv3;
            a_hn[jj] += vn.x * hv0 + vn.y * hv1 + vn.z * hv2 + vn.w * hv3;
        }
    }

#pragma unroll
    for (int jj = 0; jj < 4; ++jj) {
        red[jj][0][w][b] = a_r[jj];
        red[jj][1][w][b] = a_i[jj];
        red[jj][2][w][b] = a_in[jj];
        red[jj][3][w][b] = a_hn[jj];
    }
    __syncthreads();

    {
        const int jj = w;            // wave -> column
        const int j  = j0 + jj;
        float s_r  = red[jj][0][0][b] + red[jj][0][1][b] + red[jj][0][2][b] + red[jj][0][3][b];
        float s_i  = red[jj][1][0][b] + red[jj][1][1][b] + red[jj][1][2][b] + red[jj][1][3][b];
        float s_in = red[jj][2][0][b] + red[jj][2][1][b] + red[jj][2][2][b] + red[jj][2][3][b];
        float s_hn = red[jj][3][0][b] + red[jj][3][1][b] + red[jj][3][2][b] + red[jj][3][3][b];

        float zr = s_r + bx[j] + bh[j];
        float zi = s_i + bx[j + HH] + bh[j + HH];
        float rg = 1.f / (1.f + expf(-zr));
        float ig = 1.f / (1.f + expf(-zi));
        float ng = tanhf(s_in + bx[j + 2 * HH] + rg * (s_hn + bh[j + 2 * HH]));
        float hp = hsrc[j * BB + b];
        hdst[j * BB + b] = ng + ig * (hp - ng);
    }
}

// out[b][o] = h_last[:,b] . Wfc[o,:] + bfc[o]
__global__ __launch_bounds__(256) void k_fc(
    const float* __restrict__ h, const float* __restrict__ Wfc,
    const float* __restrict__ bfc, float* __restrict__ out)
{
    __shared__ float wrow[HH];
    __shared__ float red[4][64];
    const int o   = blockIdx.x;
    const int tid = threadIdx.x;
    const int b   = tid & 63;
    const int w   = tid >> 6;
    for (int i = tid; i < HH; i += 256) wrow[i] = Wfc[(size_t)o * HH + i];
    __syncthreads();
    float acc = 0.f;
    for (int k = w << 8; k < (w << 8) + 256; ++k) acc += wrow[k] * h[k * BB + b];
    red[w][b] = acc;
    __syncthreads();
    if (w == 0) {
        out[b * NOUT + o] = red[0][b] + red[1][b] + red[2][b] + red[3][b] + bfc[o];
    }
}

extern "C" void kernel_launch(void* const* d_in, const int* in_sizes, int n_in,
                              void* d_out, int out_size, void* d_ws, size_t ws_size,
                              hipStream_t stream) {
    (void)in_sizes; (void)n_in; (void)out_size; (void)ws_size;
    const float* x   = (const float*)d_in[0];
    const float* Wx  = (const float*)d_in[1];
    const float* bx  = (const float*)d_in[2];
    const float* Wh  = (const float*)d_in[3];
    const float* bh  = (const float*)d_in[4];
    const float* Wfc = (const float*)d_in[5];
    const float* bfc = (const float*)d_in[6];
    float* out = (float*)d_out;

    char* ws = (char*)d_ws;
    float* xT = (float*)ws;                                   // 512*256*64*4 = 33,554,432 B
    float* h0 = (float*)(ws + (size_t)33554432);              // 1024*64*4 = 262,144 B
    float* h1 = (float*)(ws + (size_t)33554432 + 262144);     // 262,144 B

    // h0 must be zero at every call (harness replays without re-poisoning).
    hipMemsetAsync(h0, 0, 262144, stream);
    k_transpose_x<<<2048, 256, 0, stream>>>(x, xT);

    for (int t = 0; t < TT; ++t) {
        const float* src = (t & 1) ? h1 : h0;
        float*       dst = (t & 1) ? h0 : h1;
        k_gru_step<<<256, 256, 0, stream>>>(xT, Wx, bx, Wh, bh, src, dst, t);
    }
    // T=512 even -> final h lands in h0
    k_fc<<<NOUT, 256, 0, stream>>>(h0, Wfc, bfc, out);
}